// Round 3
// baseline (83.846 us; speedup 1.0000x reference)
//
#include <hip/hip_runtime.h>
#include <hip/hip_bf16.h>

// B=8, T=2048, C=1024, H=64. ref: wei=(k q^T)/32, causal, softmax, @v.
// k0: wcvt  W f32 -> bf16 (Wk pre-scaled by log2e/32)
// k1: proj  x -> kp,qp (bf16 [t][64]), vt (bf16 [b][64][2048]); reads x ONCE,
//           double-buffered LDS, A/B staging register sets.
// k2: attn  split-s flash, 4 independent waves/block, compact slot decode,
//           CHUNK=2 s-tiles (128 s) per wave, bf16 partials.
// k3: combine partials -> out.

typedef __attribute__((ext_vector_type(8))) short short8;   // 8 bf16
typedef __attribute__((ext_vector_type(4))) short s4b;      // 4 bf16
typedef __attribute__((ext_vector_type(4))) float f32x4;

#define BATCH 8
#define T 2048
#define CDIM 1024
#define HD 64
#define NSLOT 1088            // split slots per batch (CHUNK=2)
#define QK_SCALE 0.04508422003f   // log2(e)/32  (exp2-domain softmax)

static __device__ __forceinline__ short f2bf(float f) {
    return __builtin_bit_cast(short, __float2bfloat16(f));   // RNE
}
static __device__ __forceinline__ float bf2f(short s) {
    unsigned u = ((unsigned)(unsigned short)s) << 16;
    return __builtin_bit_cast(float, u);
}
static __device__ __forceinline__ f32x4 mfma16(short8 a, short8 b, f32x4 c) {
    return __builtin_amdgcn_mfma_f32_16x16x32_bf16(a, b, c, 0, 0, 0);
}

// ---------------- W -> bf16 (Wk scaled) ----------------
__global__ __launch_bounds__(256) void wcvt_kernel(
    const float* __restrict__ Wk, const float* __restrict__ Wq,
    const float* __restrict__ Wv, short* __restrict__ wbf)
{
    const int gt = blockIdx.x * 256 + threadIdx.x;   // 24576 threads x 8 elems
    const int base = gt * 8;
    const int p = base >> 16;
    const int off = base & 65535;
    const float* __restrict__ src = (p == 0) ? Wk : (p == 1 ? Wq : Wv);
    const float sc = (p == 0) ? QK_SCALE : 1.0f;
    f32x4 a = *(const f32x4*)(src + off);
    f32x4 b = *(const f32x4*)(src + off + 4);
    short8 o;
#pragma unroll
    for (int e = 0; e < 4; ++e) { o[e] = f2bf(a[e] * sc); o[e + 4] = f2bf(b[e] * sc); }
    *(short8*)(wbf + p * 65536 + off) = o;
}

// ---------------- fused projection: reads x once ----------------
#define LP 72   // LDS pitch (shorts): 144B rows -> conflict-free b128 frag reads

#define PROJ_LOAD(SUF, K0) \
    { const float* xsrc = x + (size_t)(m0 + xrow) * CDIM + (K0) + xq * 8; \
      xa##SUF = *(const f32x4*)xsrc; xb##SUF = *(const f32x4*)(xsrc + 4); \
      _Pragma("unroll") for (int p = 0; p < 3; ++p) { \
        const short* wsrc = wbf + p * 65536 + wrow * CDIM + (K0) + wq * 16; \
        wr##SUF[p][0] = *(const short8*)wsrc; wr##SUF[p][1] = *(const short8*)(wsrc + 8); } }

#define PROJ_WRITE(SUF, XS, WS) \
    { short8 xv; \
      _Pragma("unroll") for (int e = 0; e < 4; ++e) { xv[e] = f2bf(xa##SUF[e]); xv[e + 4] = f2bf(xb##SUF[e]); } \
      *(short8*)&XS[xrow * LP + xq * 8] = xv; \
      _Pragma("unroll") for (int p = 0; p < 3; ++p) { \
        *(short8*)&WS[p * 4608 + wrow * LP + wq * 16] = wr##SUF[p][0]; \
        *(short8*)&WS[p * 4608 + wrow * LP + wq * 16 + 8] = wr##SUF[p][1]; } }

#define PROJ_MFMA(XS, WS) \
    _Pragma("unroll") for (int kk = 0; kk < 2; ++kk) { \
      short8 af = *(short8*)&XS[(mi * 16 + c) * LP + kk * 32 + g * 8]; \
      _Pragma("unroll") for (int p = 0; p < 3; ++p) \
        _Pragma("unroll") for (int ci = 0; ci < 2; ++ci) { \
          short8 bf = *(short8*)&WS[p * 4608 + ((ch * 2 + ci) * 16 + c) * LP + kk * 32 + g * 8]; \
          acc[p][ci] = mfma16(af, bf, acc[p][ci]); } }

__global__ __launch_bounds__(256) void proj_kernel(
    const float* __restrict__ x, const short* __restrict__ wbf,
    short* __restrict__ kp, short* __restrict__ qp, short* __restrict__ vt)
{
    __shared__ __align__(16) short xsA[32 * LP];
    __shared__ __align__(16) short xsB[32 * LP];
    __shared__ __align__(16) short wsA[3 * 64 * LP];
    __shared__ __align__(16) short wsB[3 * 64 * LP];

    const int tid = threadIdx.x;
    const int wid = tid >> 6, lane = tid & 63;
    const int g = lane >> 4, c = lane & 15;
    const int m0 = blockIdx.x * 32;
    const int mi = wid & 1, ch = wid >> 1;      // wave's m-subtile / ct-half
    const int xrow = tid >> 3, xq = tid & 7;    // x staging: 32 rows x 8 chunks
    const int wrow = tid >> 2, wq = tid & 3;    // W staging: 64 rows x 4 chunks

    f32x4 acc[3][2] = {};
    f32x4 xaA, xbA, xaB, xbB;
    short8 wrA[3][2], wrB[3][2];

    PROJ_LOAD(A, 0)
    PROJ_WRITE(A, xsA, wsA)

    for (int it = 0; it < 16; it += 2) {
        __syncthreads();
        PROJ_LOAD(B, (it + 1) * 64)
        PROJ_MFMA(xsA, wsA)
        PROJ_WRITE(B, xsB, wsB)
        __syncthreads();
        if (it < 14) { PROJ_LOAD(A, (it + 2) * 64) }
        PROJ_MFMA(xsB, wsB)
        if (it < 14) { PROJ_WRITE(A, xsA, wsA) }
    }

    // ---- epilogue: stage all three outputs, one barrier, coalesced stores
    __syncthreads();
#pragma unroll
    for (int ci = 0; ci < 2; ++ci)
#pragma unroll
        for (int r = 0; r < 4; ++r) {
            const int rl = mi * 16 + g * 4 + r;          // local row 0..31
            const int dl = (ch * 2 + ci) * 16 + c;       // out-dim 0..63
            xsA[rl * LP + dl] = f2bf(acc[0][ci][r]);     // kp
            xsB[rl * LP + dl] = f2bf(acc[1][ci][r]);     // qp
            wsA[dl * 40 + rl] = f2bf(acc[2][ci][r]);     // vt (transposed)
        }
    __syncthreads();
    {
        const int row = tid >> 3, q8 = tid & 7;
        *(short8*)&kp[(size_t)(m0 + row) * HD + q8 * 8] = *(short8*)&xsA[row * LP + q8 * 8];
        *(short8*)&qp[(size_t)(m0 + row) * HD + q8 * 8] = *(short8*)&xsB[row * LP + q8 * 8];
        const int drow = tid >> 2, q4 = tid & 3;
        const int bb = m0 >> 11, s0loc = m0 & 2047;
        *(short8*)&vt[(size_t)(bb * 64 + drow) * T + s0loc + q4 * 8] = *(short8*)&wsA[drow * 40 + q4 * 8];
    }
}

// ---------------- split-s flash attention ----------------
// SPLIT: 272 blocks/batch x 4 waves = 1088 slots/batch (CHUNK=2 s-tiles).
// slot layout per batch: group grp=j>>3 (nc=grp+1 chunks/tile), base 4*grp*(grp+1),
// then tile (j&7)*nc + ck.
template<bool SPLIT>
__global__ __launch_bounds__(256, 4) void attn_kernel(
    const short* __restrict__ kp, const short* __restrict__ qp,
    const short* __restrict__ vt, float* __restrict__ out,
    short* __restrict__ pO, float* __restrict__ pML)
{
    const int tid = threadIdx.x, wid = tid >> 6, lane = tid & 63;
    const int g = lane >> 4, c = lane & 15;
    const int b = blockIdx.y;

    int j, st0, st1, slotg = 0;
    if constexpr (SPLIT) {
        const int rem = blockIdx.x * 4 + wid;           // 0..1087
        int grp = (int)((__fsqrt_rn((float)rem + 1.0f) - 1.0f) * 0.5f);
        while (4 * (grp + 1) * (grp + 2) <= rem) ++grp;
        while (4 * grp * (grp + 1) > rem) --grp;
        const int rem2 = rem - 4 * grp * (grp + 1);
        const int jj = rem2 / (grp + 1);
        const int ck = rem2 - jj * (grp + 1);
        j = grp * 8 + jj;
        const int nst = (j >> 2) + 1;
        st0 = ck * 2;
        st1 = (st0 + 2 < nst) ? st0 + 2 : nst;
        slotg = b * NSLOT + rem;
    } else {
        j = blockIdx.x * 4 + wid;
        st0 = 0; st1 = (j >> 2) + 1;
    }
    const int t0 = j * 16;

    __shared__ __align__(16) short p_lds[4][1024];
    char* pl = (char*)(&p_lds[wid][0]);

    const short* __restrict__ kpb = kp + (size_t)b * T * HD;
    const short* __restrict__ qpb = qp + (size_t)b * T * HD;
    const short* __restrict__ vtb = vt + (size_t)b * HD * T;

    short8 afk0 = *(const short8*)&kpb[(size_t)(t0 + c) * HD + g * 8];
    short8 afk1 = *(const short8*)&kpb[(size_t)(t0 + c) * HD + 32 + g * 8];

    float m_r[4], l_r[4];
    f32x4 o[4] = {};
#pragma unroll
    for (int r = 0; r < 4; ++r) { m_r[r] = -1e30f; l_r[r] = 0.f; }

    for (int st = st0; st < st1; ++st) {
        const int s0 = st * 64;
        f32x4 s_acc[4] = {};
#pragma unroll
        for (int ct = 0; ct < 4; ++ct) {
            short8 bq0 = *(const short8*)&qpb[(size_t)(s0 + ct * 16 + c) * HD + g * 8];
            short8 bq1 = *(const short8*)&qpb[(size_t)(s0 + ct * 16 + c) * HD + 32 + g * 8];
            s_acc[ct] = mfma16(afk0, bq0, s_acc[ct]);
            s_acc[ct] = mfma16(afk1, bq1, s_acc[ct]);
        }

        // V prefetch: independent of softmax, hides under the reduce chain
        short8 vb[4][2];
#pragma unroll
        for (int dt = 0; dt < 4; ++dt) {
            vb[dt][0] = *(const short8*)&vtb[(size_t)(dt * 16 + c) * T + s0 + g * 8];
            vb[dt][1] = *(const short8*)&vtb[(size_t)(dt * 16 + c) * T + s0 + 32 + g * 8];
        }

        const bool diag = (s0 + 63 > t0);
        float sv[4][4];
#pragma unroll
        for (int ct = 0; ct < 4; ++ct)
#pragma unroll
            for (int r = 0; r < 4; ++r) {
                float v = s_acc[ct][r];              // scale folded into Wk
                if (diag) {
                    int s = s0 + ct * 16 + c;
                    int t = t0 + g * 4 + r;
                    if (s > t) v = -1e30f;
                }
                sv[ct][r] = v;
            }

        float alpha[4];
#pragma unroll
        for (int r = 0; r < 4; ++r) {
            float mx = fmaxf(fmaxf(sv[0][r], sv[1][r]), fmaxf(sv[2][r], sv[3][r]));
#pragma unroll
            for (int off = 1; off < 16; off <<= 1)
                mx = fmaxf(mx, __shfl_xor(mx, off));
            float mnew = fmaxf(m_r[r], mx);
            alpha[r] = exp2f(m_r[r] - mnew);
            m_r[r] = mnew;
        }

        float rsum[4] = {0.f, 0.f, 0.f, 0.f};
        short pv16[4][4];
#pragma unroll
        for (int ct = 0; ct < 4; ++ct)
#pragma unroll
            for (int r = 0; r < 4; ++r) {
                float pe = exp2f(sv[ct][r] - m_r[r]);
                rsum[r] += pe;
                pv16[ct][r] = f2bf(pe);
            }
#pragma unroll
        for (int r = 0; r < 4; ++r) {
#pragma unroll
            for (int off = 1; off < 16; off <<= 1)
                rsum[r] += __shfl_xor(rsum[r], off);
            l_r[r] = l_r[r] * alpha[r] + rsum[r];
        }
#pragma unroll
        for (int dt = 0; dt < 4; ++dt)
#pragma unroll
            for (int r = 0; r < 4; ++r)
                o[dt][r] *= alpha[r];

        // transpose P via XOR-swizzled LDS
#pragma unroll
        for (int ct = 0; ct < 4; ++ct)
#pragma unroll
            for (int r = 0; r < 4; ++r) {
                int prow = g * 4 + r;
                int ps = ct * 16 + c;
                *(short*)(pl + prow * 128 + ((ps * 2) ^ ((prow & 7) << 4))) = pv16[ct][r];
            }
        short8 pa0 = *(short8*)(pl + c * 128 + (((g * 8) * 2) ^ ((c & 7) << 4)));
        short8 pa1 = *(short8*)(pl + c * 128 + (((32 + g * 8) * 2) ^ ((c & 7) << 4)));
#pragma unroll
        for (int dt = 0; dt < 4; ++dt) {
            o[dt] = mfma16(pa0, vb[dt][0], o[dt]);
            o[dt] = mfma16(pa1, vb[dt][1], o[dt]);
        }
    }

    if constexpr (!SPLIT) {
#pragma unroll
        for (int dt = 0; dt < 4; ++dt)
#pragma unroll
            for (int r = 0; r < 4; ++r)
                out[((size_t)b * T + t0 + g * 4 + r) * HD + dt * 16 + c] = o[dt][r] / l_r[r];
    } else {
        short* po = pO + (size_t)slotg * 1024;   // layout [dt][lane][r], 8B/lane stores
#pragma unroll
        for (int dt = 0; dt < 4; ++dt) {
            s4b pk = { f2bf(o[dt][0]), f2bf(o[dt][1]), f2bf(o[dt][2]), f2bf(o[dt][3]) };
            *(s4b*)&po[dt * 256 + lane * 4] = pk;
        }
        if (c == 0) {
#pragma unroll
            for (int r = 0; r < 4; ++r) {
                pML[slotg * 32 + g * 4 + r] = m_r[r];
                pML[slotg * 32 + 16 + g * 4 + r] = l_r[r];
            }
        }
    }
}

// ---------------- combine ----------------
__global__ __launch_bounds__(256) void combine_kernel(
    const short* __restrict__ pO, const float* __restrict__ pML,
    float* __restrict__ out)
{
    const int j = blockIdx.x, b = blockIdx.y;
    const int tid = threadIdx.x, dt = tid >> 6, lane = tid & 63;
    const int g = lane >> 4, c = lane & 15;
    const int grp = j >> 3, nc = grp + 1;
    const int base = b * NSLOT + 4 * grp * (grp + 1) + (j & 7) * nc;

    float M[4] = { -1e30f, -1e30f, -1e30f, -1e30f };
    for (int cq = 0; cq < nc; ++cq)
#pragma unroll
        for (int r = 0; r < 4; ++r)
            M[r] = fmaxf(M[r], pML[(size_t)(base + cq) * 32 + g * 4 + r]);

    f32x4 accd = {};
    float L[4] = { 0.f, 0.f, 0.f, 0.f };
    for (int cq = 0; cq < nc; ++cq) {
        float w[4];
#pragma unroll
        for (int r = 0; r < 4; ++r) {
            float m = pML[(size_t)(base + cq) * 32 + g * 4 + r];
            w[r] = exp2f(m - M[r]);
            L[r] += w[r] * pML[(size_t)(base + cq) * 32 + 16 + g * 4 + r];
        }
        s4b pk = *(const s4b*)&pO[(size_t)(base + cq) * 1024 + dt * 256 + lane * 4];
#pragma unroll
        for (int r = 0; r < 4; ++r)
            accd[r] += w[r] * bf2f(pk[r]);
    }
#pragma unroll
    for (int r = 0; r < 4; ++r)
        out[((size_t)b * T + j * 16 + g * 4 + r) * HD + dt * 16 + c] = accd[r] / L[r];
}

extern "C" void kernel_launch(void* const* d_in, const int* in_sizes, int n_in,
                              void* d_out, int out_size, void* d_ws, size_t ws_size,
                              hipStream_t stream) {
    const float* x  = (const float*)d_in[0];
    const float* Wk = (const float*)d_in[1];
    const float* Wq = (const float*)d_in[2];
    const float* Wv = (const float*)d_in[3];
    float* out = (float*)d_out;

    short* kp  = (short*)d_ws;                          // [16384][64] bf16
    short* qp  = kp + (size_t)BATCH * T * HD;           // [16384][64] bf16
    short* vt  = qp + (size_t)BATCH * T * HD;           // [8][64][2048] bf16
    short* wbf = vt + (size_t)BATCH * T * HD;           // [3][64][1024] bf16
    short* pO  = wbf + 3 * 65536;                       // [8704][1024] bf16
    float* pML = (float*)(pO + (size_t)BATCH * NSLOT * 1024);  // [8704][32] f32

    const size_t need = (size_t)((char*)(pML + (size_t)BATCH * NSLOT * 32) - (char*)d_ws);

    wcvt_kernel<<<96, 256, 0, stream>>>(Wk, Wq, Wv, wbf);
    proj_kernel<<<512, 256, 0, stream>>>(x, wbf, kp, qp, vt);
    if (ws_size >= need) {
        attn_kernel<true><<<dim3(272, BATCH), 256, 0, stream>>>(kp, qp, vt, nullptr, pO, pML);
        combine_kernel<<<dim3(128, BATCH), 256, 0, stream>>>(pO, pML, out);
    } else {
        attn_kernel<false><<<dim3(32, BATCH), 256, 0, stream>>>(kp, qp, vt, out, nullptr, nullptr);
    }
}